// Round 1
// baseline (341.450 us; speedup 1.0000x reference)
//
#include <hip/hip_runtime.h>
#include <stdint.h>
#include <stddef.h>

// ---------- types ----------
typedef __bf16 bf16;
typedef __bf16 bf16x8 __attribute__((ext_vector_type(8)));
typedef float  f32x4  __attribute__((ext_vector_type(4)));
typedef unsigned short ush;
typedef ush ush8 __attribute__((ext_vector_type(8)));

// ---------- problem sizes ----------
#define B_  4
#define S_  2048
#define E_  1024
#define H_  16
#define D_  64
#define M_  (B_*S_)      // 8192 rows
#define K_  E_           // 1024 reduction
#define LOG2E 1.44269504088896340736f

// ---------- helpers ----------
__device__ __forceinline__ void gload_lds16(const void* g, void* l) {
  // async global->LDS, 16B per lane; LDS dest = wave-uniform base + lane*16
  __builtin_amdgcn_global_load_lds((const __attribute__((address_space(1))) void*)g,
                                   (__attribute__((address_space(3))) void*)l, 16, 0, 0);
}
__device__ __forceinline__ f32x4 mfma16(bf16x8 a, bf16x8 b, f32x4 c) {
  return __builtin_amdgcn_mfma_f32_16x16x32_bf16(a, b, c, 0, 0, 0);
}
// 128B rows (8 x 16B chunks): chunk ^= row&7
__device__ __forceinline__ int swz8(int row, int ch) { return ch ^ (row & 7); }
// 64B rows (4 x 16B chunks): chunk ^= (row>>1)&3
__device__ __forceinline__ int swz4(int row, int ch) { return ch ^ ((row >> 1) & 3); }

// ---------- prep kernels ----------
__global__ void cast_f32_bf16(const float* __restrict__ src, bf16* __restrict__ dst, int n4) {
  int idx = blockIdx.x * blockDim.x + threadIdx.x;
  int stride = gridDim.x * blockDim.x;
  for (int i = idx; i < n4; i += stride) {
    float4 v = ((const float4*)src)[i];
    union { bf16 b[4]; ushort4 u; } cv;
    cv.b[0] = (bf16)v.x; cv.b[1] = (bf16)v.y; cv.b[2] = (bf16)v.z; cv.b[3] = (bf16)v.w;
    ((ushort4*)dst)[i] = cv.u;
  }
}

// pack Wq|Wk|Wv [H,E,D] -> Wp [3*1024][1024] with row n = which*1024 + h*64 + d, col e
__global__ void pack_w(const float* __restrict__ Wq, const float* __restrict__ Wk,
                       const float* __restrict__ Wv, bf16* __restrict__ Wp) {
  int idx = blockIdx.x * blockDim.x + threadIdx.x;
  int stride = gridDim.x * blockDim.x;
  const int total = 3 * 1024 * 1024;
  for (int o = idx; o < total; o += stride) {
    int which = o >> 20;
    int rem = o & 1048575;
    int n = rem >> 10, e = rem & 1023;
    int h = n >> 6, d = n & 63;
    const float* s = (which == 0) ? Wq : (which == 1 ? Wk : Wv);
    Wp[o] = (bf16)s[((size_t)h * 1024 + e) * 64 + d];
  }
}

// ---------- GEMM: C[M][N] = A[M][K] * Bm[N][K]^T ----------
// MODE 0: scatter bf16 into Q/K/V [B,H,S,D] (+bias). MODE 1: fp32 out (+bias).
template <int MODE>
__launch_bounds__(256, 2)
__global__ void gemm_kernel(const bf16* __restrict__ A, const bf16* __restrict__ Bm,
                            int Ntot,
                            const float* __restrict__ bias0, const float* __restrict__ bias1,
                            const float* __restrict__ bias2,
                            bf16* __restrict__ Qo, bf16* __restrict__ Ko, bf16* __restrict__ Vo,
                            float* __restrict__ Fo) {
  __shared__ __align__(16) bf16 lds_a[2][128 * 32];
  __shared__ __align__(16) bf16 lds_b[2][128 * 32];
  const int tid = threadIdx.x;
  const int lane = tid & 63;
  const int w = tid >> 6;
  const int wr = w >> 1, wc = w & 1;
  const int nblk = Ntot >> 7;
  const int mt = blockIdx.x / nblk, nt = blockIdx.x % nblk;
  const int m0 = mt << 7, n0 = nt << 7;

  f32x4 acc[4][4] = {};

  auto stage = [&](int buf, int kt) {
    #pragma unroll
    for (int i = 0; i < 2; ++i) {
      int cb = (w * 2 + i) * 64;          // wave-uniform chunk base
      int cid = cb + lane;                // this lane's 16B chunk (0..511)
      int row = cid >> 2, cir = cid & 3;  // 4 chunks per 64B row
      int lch = swz4(row, cir);           // pre-swizzle SOURCE so swizzled READ works
      const bf16* ga = A  + (size_t)(m0 + row) * K_ + kt * 32 + lch * 8;
      const bf16* gb = Bm + (size_t)(n0 + row) * K_ + kt * 32 + lch * 8;
      gload_lds16(ga, &lds_a[buf][cb * 8]);
      gload_lds16(gb, &lds_b[buf][cb * 8]);
    }
  };

  const int NT = K_ / 32;
  stage(0, 0);
  for (int kt = 0; kt < NT; ++kt) {
    if (kt + 1 < NT) stage((kt + 1) & 1, kt + 1);
    __syncthreads();  // drains vmcnt: staged tiles ready
    const bf16x8* pa = (const bf16x8*)&lds_a[kt & 1][0];
    const bf16x8* pb = (const bf16x8*)&lds_b[kt & 1][0];
    bf16x8 af[4], bfr[4];
    #pragma unroll
    for (int mb = 0; mb < 4; ++mb) {
      int row = wr * 64 + mb * 16 + (lane & 15);
      af[mb] = pa[row * 4 + swz4(row, lane >> 4)];
    }
    #pragma unroll
    for (int nb = 0; nb < 4; ++nb) {
      int row = wc * 64 + nb * 16 + (lane & 15);
      bfr[nb] = pb[row * 4 + swz4(row, lane >> 4)];
    }
    #pragma unroll
    for (int mb = 0; mb < 4; ++mb)
      #pragma unroll
      for (int nb = 0; nb < 4; ++nb)
        acc[mb][nb] = mfma16(af[mb], bfr[nb], acc[mb][nb]);
    __syncthreads();  // all reads done before buffer reuse
  }

  // epilogue: C/D layout col=lane&15, row=(lane>>4)*4+reg  [m89-verified]
  #pragma unroll
  for (int mb = 0; mb < 4; ++mb) {
    #pragma unroll
    for (int nb = 0; nb < 4; ++nb) {
      #pragma unroll
      for (int r = 0; r < 4; ++r) {
        int mi = m0 + wr * 64 + mb * 16 + (lane >> 4) * 4 + r;
        int ni = n0 + wc * 64 + nb * 16 + (lane & 15);
        float v = acc[mb][nb][r];
        if (MODE == 0) {
          int which = ni >> 10;
          int col = ni & 1023;
          const float* bp = (which == 0) ? bias0 : (which == 1 ? bias1 : bias2);
          v += bp[col];
          int h = col >> 6, d = col & 63;
          int b = mi >> 11, s = mi & 2047;  // S_=2048
          bf16* dst = (which == 0) ? Qo : (which == 1 ? Ko : Vo);
          dst[(((size_t)(b * H_ + h)) * S_ + s) * D_ + d] = (bf16)v;
        } else {
          Fo[(size_t)mi * E_ + ni] = v + bias0[ni];
        }
      }
    }
  }
}

// ---------- V transpose: V[B,H,S,D] -> Vt[B,H,D,S] ----------
__global__ void transpose_v(const bf16* __restrict__ V, bf16* __restrict__ Vt) {
  __shared__ ush t[64 * 65];
  const int bh = blockIdx.y;
  const int s0 = blockIdx.x * 64;
  const int tid = threadIdx.x;
  #pragma unroll
  for (int i = 0; i < 2; ++i) {
    int cid = tid + 256 * i;            // 0..511: 64 rows x 8 chunks
    int r = cid >> 3, c = cid & 7;
    ush8 val = *(const ush8*)(V + ((size_t)bh * S_ + s0 + r) * D_ + c * 8);
    #pragma unroll
    for (int j = 0; j < 8; ++j) t[(c * 8 + j) * 65 + r] = val[j];
  }
  __syncthreads();
  #pragma unroll
  for (int i = 0; i < 2; ++i) {
    int cid = tid + 256 * i;
    int d = cid >> 3, sc = cid & 7;
    ush8 o;
    #pragma unroll
    for (int j = 0; j < 8; ++j) o[j] = t[d * 65 + sc * 8 + j];
    *(ush8*)(Vt + ((size_t)bh * D_ + d) * S_ + s0 + sc * 8) = o;
  }
}

// ---------- flash attention (causal) ----------
// grid (S/64, B*H); 4 waves x 16 q-rows. K,Vt staged in LDS (swz8). P via per-wave LDS.
__launch_bounds__(256, 2)
__global__ void attn_kernel(const bf16* __restrict__ Q, const bf16* __restrict__ K,
                            const bf16* __restrict__ Vt, bf16* __restrict__ Oc) {
  __shared__ __align__(16) bf16 k_lds[64 * 64];
  __shared__ __align__(16) bf16 v_lds[64 * 64];   // holds Vt tile: [d][s_local]
  __shared__ __align__(16) bf16 p_lds[4][16 * 64];
  const int tid = threadIdx.x, lane = tid & 63, w = tid >> 6;
  const int bh = blockIdx.y;
  const int q0 = blockIdx.x * 64;
  const int qr = q0 + w * 16;

  // Q fragments (A-operand), pre-scaled by 1/sqrt(D)=0.125 (exact in bf16)
  bf16x8 qf[2];
  #pragma unroll
  for (int kg = 0; kg < 2; ++kg) {
    bf16x8 v = *(const bf16x8*)(Q + ((size_t)bh * S_ + qr + (lane & 15)) * D_ + kg * 32 + (lane >> 4) * 8);
    #pragma unroll
    for (int j = 0; j < 8; ++j) v[j] = (bf16)((float)v[j] * 0.125f);
    qf[kg] = v;
  }

  float mstate[4], lstate[4];
  f32x4 oacc[4];
  #pragma unroll
  for (int r = 0; r < 4; ++r) { mstate[r] = -1e30f; lstate[r] = 0.f; }
  #pragma unroll
  for (int db = 0; db < 4; ++db) oacc[db] = f32x4{0.f, 0.f, 0.f, 0.f};

  const int ntile = (q0 >> 6) + 1;
  for (int t = 0; t < ntile; ++t) {
    const int kv0 = t * 64;
    __syncthreads();  // previous tile fully consumed
    #pragma unroll
    for (int i = 0; i < 2; ++i) {
      int cb = (w * 2 + i) * 64;
      int cid = cb + lane;
      int row = cid >> 3, cir = cid & 7;  // 8 chunks per 128B row
      int lch = swz8(row, cir);
      gload_lds16(K  + ((size_t)bh * S_ + kv0 + row) * D_ + lch * 8, &k_lds[cb * 8]);
      gload_lds16(Vt + ((size_t)bh * D_ + row) * S_ + kv0 + lch * 8, &v_lds[cb * 8]);
    }
    __syncthreads();  // tiles staged

    // scores: S = (Q*0.125) . K^T   -> D-layout: row=q(reg), col=kj(lane&15)
    f32x4 sc[4];
    #pragma unroll
    for (int cb2 = 0; cb2 < 4; ++cb2) {
      f32x4 s = f32x4{0.f, 0.f, 0.f, 0.f};
      #pragma unroll
      for (int kg = 0; kg < 2; ++kg) {
        int row = (lane & 15) + 16 * cb2;
        bf16x8 kf = *(const bf16x8*)&k_lds[row * 64 + swz8(row, 4 * kg + (lane >> 4)) * 8];
        s = mfma16(qf[kg], kf, s);
      }
      sc[cb2] = s;
    }
    if (kv0 == q0) {  // diagonal tile: causal mask col > row
      #pragma unroll
      for (int cb2 = 0; cb2 < 4; ++cb2)
        #pragma unroll
        for (int r = 0; r < 4; ++r) {
          int col = kv0 + cb2 * 16 + (lane & 15);
          int rowq = qr + (lane >> 4) * 4 + r;
          if (col > rowq) sc[cb2][r] = -1e30f;
        }
    }

    // online softmax (per 16-lane row group)
    float alpha[4];
    #pragma unroll
    for (int r = 0; r < 4; ++r) {
      float m = fmaxf(fmaxf(sc[0][r], sc[1][r]), fmaxf(sc[2][r], sc[3][r]));
      #pragma unroll
      for (int off = 1; off < 16; off <<= 1) m = fmaxf(m, __shfl_xor(m, off, 64));
      float mnew = fmaxf(mstate[r], m);
      alpha[r] = exp2f((mstate[r] - mnew) * LOG2E);
      mstate[r] = mnew;
    }
    float rs[4] = {0.f, 0.f, 0.f, 0.f};
    #pragma unroll
    for (int cb2 = 0; cb2 < 4; ++cb2)
      #pragma unroll
      for (int r = 0; r < 4; ++r) {
        float p = exp2f((sc[cb2][r] - mstate[r]) * LOG2E);
        sc[cb2][r] = p;
        rs[r] += p;
      }
    #pragma unroll
    for (int r = 0; r < 4; ++r) {
      float s = rs[r];
      #pragma unroll
      for (int off = 1; off < 16; off <<= 1) s += __shfl_xor(s, off, 64);
      lstate[r] = lstate[r] * alpha[r] + s;
    }
    #pragma unroll
    for (int db = 0; db < 4; ++db)
      #pragma unroll
      for (int r = 0; r < 4; ++r) oacc[db][r] *= alpha[r];

    // P: D-layout -> LDS (swz8) -> A-layout fragments (per-wave private region)
    bf16* pl = &p_lds[w][0];
    #pragma unroll
    for (int cb2 = 0; cb2 < 4; ++cb2)
      #pragma unroll
      for (int r = 0; r < 4; ++r) {
        int rowp = (lane >> 4) * 4 + r;
        int col = (lane & 15) + 16 * cb2;
        int ch = swz8(rowp, col >> 3);
        pl[rowp * 64 + ch * 8 + (col & 7)] = (bf16)sc[cb2][r];
      }
    bf16x8 pf[2];
    #pragma unroll
    for (int kg = 0; kg < 2; ++kg) {
      int rowp = lane & 15;
      pf[kg] = *(const bf16x8*)&pl[rowp * 64 + swz8(rowp, 4 * kg + (lane >> 4)) * 8];
    }
    // O += P * V  (B-frag from Vt tile: contiguous in s_local)
    #pragma unroll
    for (int db = 0; db < 4; ++db) {
      #pragma unroll
      for (int kg = 0; kg < 2; ++kg) {
        int row = (lane & 15) + 16 * db;
        bf16x8 vf = *(const bf16x8*)&v_lds[row * 64 + swz8(row, 4 * kg + (lane >> 4)) * 8];
        oacc[db] = mfma16(pf[kg], vf, oacc[db]);
      }
    }
  }

  // write concat [B,S,H*D] bf16
  const int b = bh >> 4, h = bh & 15;
  #pragma unroll
  for (int db = 0; db < 4; ++db)
    #pragma unroll
    for (int r = 0; r < 4; ++r) {
      int srow = qr + (lane >> 4) * 4 + r;
      int d = db * 16 + (lane & 15);
      float v = oacc[db][r] / lstate[r];
      Oc[((size_t)(b * S_ + srow)) * E_ + h * D_ + d] = (bf16)v;
    }
}

// ---------- launcher ----------
extern "C" void kernel_launch(void* const* d_in, const int* in_sizes, int n_in,
                              void* d_out, int out_size, void* d_ws, size_t ws_size,
                              hipStream_t stream) {
  const float* x  = (const float*)d_in[0];
  const float* Wq = (const float*)d_in[1];
  const float* bq = (const float*)d_in[2];
  const float* Wk = (const float*)d_in[3];
  const float* bk = (const float*)d_in[4];
  const float* Wv = (const float*)d_in[5];
  const float* bv = (const float*)d_in[6];
  const float* Wo = (const float*)d_in[7];
  const float* bo = (const float*)d_in[8];
  float* out = (float*)d_out;

  uint8_t* ws = (uint8_t*)d_ws;
  // layout (bytes). concat reuses Xbf region (X dead after QKV GEMM).
  bf16* Xbf   = (bf16*)(ws + 0);           // 16.8MB  [M][K] ; later: concat
  bf16* Wpack = (bf16*)(ws + 16777216);    // 6.3MB   [3072][1024]
  bf16* Wot   = (bf16*)(ws + 23068672);    // 2.1MB   [1024][1024] (= Wo cast)
  bf16* Qb    = (bf16*)(ws + 25165824);    // 16.8MB  [B,H,S,D]
  bf16* Kb    = (bf16*)(ws + 41943040);    // 16.8MB
  bf16* Vb    = (bf16*)(ws + 58720256);    // 16.8MB
  bf16* Vtb   = (bf16*)(ws + 75497472);    // 16.8MB  [B,H,D,S]
  bf16* Cc    = Xbf;                       // concat [M][E] bf16 (reuse)

  // prep
  cast_f32_bf16<<<2048, 256, 0, stream>>>(x,  Xbf, (M_ * K_) / 4);
  cast_f32_bf16<<<1024, 256, 0, stream>>>(Wo, Wot, (E_ * E_) / 4);
  pack_w<<<2048, 256, 0, stream>>>(Wq, Wk, Wv, Wpack);

  // QKV projection: [8192x1024] x [1024x3072]
  gemm_kernel<0><<<dim3(64 * 24), 256, 0, stream>>>(Xbf, Wpack, 3072, bq, bk, bv,
                                                    Qb, Kb, Vb, nullptr);
  // V -> Vt
  transpose_v<<<dim3(S_ / 64, B_ * H_), 256, 0, stream>>>(Vb, Vtb);

  // flash attention -> concat
  attn_kernel<<<dim3(S_ / 64, B_ * H_), 256, 0, stream>>>(Qb, Kb, Vtb, Cc);

  // output projection: [8192x1024] x [1024x1024] + bo -> fp32
  gemm_kernel<1><<<dim3(64 * 8), 256, 0, stream>>>(Cc, Wot, 1024, bo, nullptr, nullptr,
                                                   nullptr, nullptr, nullptr, out);
}

// Round 3
// 242.082 us; speedup vs baseline: 1.4105x; 1.4105x over previous
//
#include <hip/hip_runtime.h>
#include <stdint.h>
#include <stddef.h>

// ---------- types ----------
typedef __bf16 bf16;
typedef __bf16 bf16x8 __attribute__((ext_vector_type(8)));
typedef __bf16 bf16x4 __attribute__((ext_vector_type(4)));
typedef float  f32x4  __attribute__((ext_vector_type(4)));
typedef float  f32x16 __attribute__((ext_vector_type(16)));
typedef unsigned short ush;
typedef ush ush8 __attribute__((ext_vector_type(8)));
typedef unsigned int uint;

// ---------- problem sizes ----------
#define B_  4
#define S_  2048
#define E_  1024
#define H_  16
#define D_  64
#define M_  (B_*S_)      // 8192 rows
#define K_  E_           // 1024 reduction
// 0.125 (1/sqrt(D)) * log2(e): QKV epilogue folds this into Q -> softmax in exp2 domain
#define QSCALE 0.18033688011112042f

// ---------- helpers ----------
__device__ __forceinline__ void gload_lds16(const void* g, void* l) {
  __builtin_amdgcn_global_load_lds((const __attribute__((address_space(1))) void*)g,
                                   (__attribute__((address_space(3))) void*)l, 16, 0, 0);
}
__device__ __forceinline__ f32x4 mfma16(bf16x8 a, bf16x8 b, f32x4 c) {
  return __builtin_amdgcn_mfma_f32_16x16x32_bf16(a, b, c, 0, 0, 0);
}
__device__ __forceinline__ f32x16 mfma32(bf16x8 a, bf16x8 b, f32x16 c) {
  return __builtin_amdgcn_mfma_f32_32x32x16_bf16(a, b, c, 0, 0, 0);
}
__device__ __forceinline__ int swz4(int row, int ch) { return ch ^ ((row >> 1) & 3); }
__device__ __forceinline__ uint cvtpk(float lo, float hi) {
  uint r;
  asm("v_cvt_pk_bf16_f32 %0, %1, %2" : "=v"(r) : "v"(lo), "v"(hi));
  return r;
}

// ---------- prep kernels ----------
__global__ void cast_f32_bf16(const float* __restrict__ src, bf16* __restrict__ dst, int n4) {
  int idx = blockIdx.x * blockDim.x + threadIdx.x;
  int stride = gridDim.x * blockDim.x;
  for (int i = idx; i < n4; i += stride) {
    float4 v = ((const float4*)src)[i];
    union { bf16 b[4]; ushort4 u; } cv;
    cv.b[0] = (bf16)v.x; cv.b[1] = (bf16)v.y; cv.b[2] = (bf16)v.z; cv.b[3] = (bf16)v.w;
    ((ushort4*)dst)[i] = cv.u;
  }
}

// pack Wq|Wk|Wv [H,E,D] -> Wp[n][e], n = which*1024 + h*64 + d. LDS-tiled transpose:
// coalesced float4 reads of [e][d] rows, 16B bf16 writes of [n][e] rows.
__global__ void pack_w_t(const float* __restrict__ Wq, const float* __restrict__ Wk,
                         const float* __restrict__ Wv, bf16* __restrict__ Wp) {
  __shared__ float t[64][65];
  const int tid = threadIdx.x;
  const int wh = blockIdx.y;          // 0..47
  const int which = wh >> 4, h = wh & 15;
  const int e0 = blockIdx.x << 6;
  const float* src = (which == 0) ? Wq : (which == 1 ? Wk : Wv);
  src += (size_t)h * (E_ * D_);       // [E][D] for this head
  #pragma unroll
  for (int i = 0; i < 4; ++i) {
    int fi = tid + 256 * i;           // 1024 float4 chunks = 64 e-rows x 16
    int e = fi >> 4, c = fi & 15;
    float4 v = *(const float4*)(src + (size_t)(e0 + e) * D_ + c * 4);
    t[c * 4 + 0][e] = v.x; t[c * 4 + 1][e] = v.y;
    t[c * 4 + 2][e] = v.z; t[c * 4 + 3][e] = v.w;
  }
  __syncthreads();
  #pragma unroll
  for (int i = 0; i < 2; ++i) {
    int cid = tid + 256 * i;          // 512 chunks = 64 d-rows x 8
    int d = cid >> 3, cc = cid & 7;
    ush8 o;
    #pragma unroll
    for (int j = 0; j < 8; ++j) {
      union { bf16 b; ush u; } cv; cv.b = (bf16)t[d][cc * 8 + j]; o[j] = cv.u;
    }
    *(ush8*)(Wp + ((size_t)which * 1024 + h * 64 + d) * K_ + e0 + cc * 8) = o;
  }
}

// ---------- GEMM: C[M][N] = A[M][K] * Bm[N][K]^T ----------
template <int MODE>
__launch_bounds__(256, 2)
__global__ void gemm_kernel(const bf16* __restrict__ A, const bf16* __restrict__ Bm,
                            int Ntot,
                            const float* __restrict__ bias0, const float* __restrict__ bias1,
                            const float* __restrict__ bias2,
                            bf16* __restrict__ Qo, bf16* __restrict__ Ko, bf16* __restrict__ Vo,
                            float* __restrict__ Fo) {
  __shared__ __align__(16) bf16 lds_a[2][128 * 32];
  __shared__ __align__(16) bf16 lds_b[2][128 * 32];
  const int tid = threadIdx.x;
  const int lane = tid & 63;
  const int w = tid >> 6;
  const int wr = w >> 1, wc = w & 1;
  const int nblk = Ntot >> 7;
  const int mt = blockIdx.x / nblk, nt = blockIdx.x % nblk;
  const int m0 = mt << 7, n0 = nt << 7;

  f32x4 acc[4][4] = {};

  auto stage = [&](int buf, int kt) {
    #pragma unroll
    for (int i = 0; i < 2; ++i) {
      int cb = (w * 2 + i) * 64;
      int cid = cb + lane;
      int row = cid >> 2, cir = cid & 3;
      int lch = swz4(row, cir);
      const bf16* ga = A  + (size_t)(m0 + row) * K_ + kt * 32 + lch * 8;
      const bf16* gb = Bm + (size_t)(n0 + row) * K_ + kt * 32 + lch * 8;
      gload_lds16(ga, &lds_a[buf][cb * 8]);
      gload_lds16(gb, &lds_b[buf][cb * 8]);
    }
  };

  const int NT = K_ / 32;
  stage(0, 0);
  for (int kt = 0; kt < NT; ++kt) {
    if (kt + 1 < NT) stage((kt + 1) & 1, kt + 1);
    __syncthreads();
    const bf16x8* pa = (const bf16x8*)&lds_a[kt & 1][0];
    const bf16x8* pb = (const bf16x8*)&lds_b[kt & 1][0];
    bf16x8 af[4], bfr[4];
    #pragma unroll
    for (int mb = 0; mb < 4; ++mb) {
      int row = wr * 64 + mb * 16 + (lane & 15);
      af[mb] = pa[row * 4 + swz4(row, lane >> 4)];
    }
    #pragma unroll
    for (int nb = 0; nb < 4; ++nb) {
      int row = wc * 64 + nb * 16 + (lane & 15);
      bfr[nb] = pb[row * 4 + swz4(row, lane >> 4)];
    }
    #pragma unroll
    for (int mb = 0; mb < 4; ++mb)
      #pragma unroll
      for (int nb = 0; nb < 4; ++nb)
        acc[mb][nb] = mfma16(af[mb], bfr[nb], acc[mb][nb]);
    __syncthreads();
  }

  #pragma unroll
  for (int mb = 0; mb < 4; ++mb) {
    #pragma unroll
    for (int nb = 0; nb < 4; ++nb) {
      #pragma unroll
      for (int r = 0; r < 4; ++r) {
        int mi = m0 + wr * 64 + mb * 16 + (lane >> 4) * 4 + r;
        int ni = n0 + wc * 64 + nb * 16 + (lane & 15);
        float v = acc[mb][nb][r];
        if (MODE == 0) {
          int which = ni >> 10;
          int col = ni & 1023;
          const float* bp = (which == 0) ? bias0 : (which == 1 ? bias1 : bias2);
          v += bp[col];
          if (which == 0) v *= QSCALE;   // fold 1/sqrt(D)*log2e into Q
          int h = col >> 6, d = col & 63;
          int b = mi >> 11, s = mi & 2047;
          bf16* dst = (which == 0) ? Qo : (which == 1 ? Ko : Vo);
          dst[(((size_t)(b * H_ + h)) * S_ + s) * D_ + d] = (bf16)v;
        } else {
          Fo[(size_t)mi * E_ + ni] = v + bias0[ni];
        }
      }
    }
  }
}

// ---------- V transpose: V[B,H,S,D] -> Vt[B,H,D,S] ----------
__global__ void transpose_v(const bf16* __restrict__ V, bf16* __restrict__ Vt) {
  __shared__ ush t[64 * 65];
  const int bh = blockIdx.y;
  const int s0 = blockIdx.x * 64;
  const int tid = threadIdx.x;
  #pragma unroll
  for (int i = 0; i < 2; ++i) {
    int cid = tid + 256 * i;
    int r = cid >> 3, c = cid & 7;
    ush8 val = *(const ush8*)(V + ((size_t)bh * S_ + s0 + r) * D_ + c * 8);
    #pragma unroll
    for (int j = 0; j < 8; ++j) t[(c * 8 + j) * 65 + r] = val[j];
  }
  __syncthreads();
  #pragma unroll
  for (int i = 0; i < 2; ++i) {
    int cid = tid + 256 * i;
    int d = cid >> 3, sc = cid & 7;
    ush8 o;
    #pragma unroll
    for (int j = 0; j < 8; ++j) o[j] = t[d * 65 + sc * 8 + j];
    *(ush8*)(Vt + ((size_t)bh * D_ + d) * S_ + s0 + sc * 8) = o;
  }
}

// ---------- flash attention (causal), swapped-QK^T 32x32 structure ----------
// grid (16, B*H); 4 waves x 32 q-rows = 128 q/block, KVBLK=64.
// S^T = mfma(K, Q): lane owns q = lane&31; kv regs crow(r,hi)=(r&3)+8*(r>>2)+4*hi.
// O^T = mfma(Vt, P^T): col = q = lane&31 -> softmax state fully lane-local.
__launch_bounds__(256, 3)
__global__ void attn_kernel(const bf16* __restrict__ Q, const bf16* __restrict__ K,
                            const bf16* __restrict__ Vt, bf16* __restrict__ Oc) {
  __shared__ __align__(16) bf16 k_lds[64 * 64];
  __shared__ __align__(16) bf16 v_lds[64 * 64];   // Vt tile: [d][kv_local]
  const int tid = threadIdx.x, lane = tid & 63, w = tid >> 6;
  const int hi = lane >> 5, ln = lane & 31;
  const int bh = blockIdx.y;
  const int jt = (int)(gridDim.x - 1) - (int)blockIdx.x;  // longest blocks first
  const int q0 = jt * 128;
  const int qb = q0 + w * 32;
  const int qg = qb + ln;

  // Q B-fragments (pre-scaled in GEMM): k-dim d = 16*kc + 8*hi + j
  bf16x8 qf[4];
  const bf16* qrow = Q + ((size_t)bh * S_ + qg) * D_;
  #pragma unroll
  for (int kc = 0; kc < 4; ++kc)
    qf[kc] = *(const bf16x8*)(qrow + (2 * kc + hi) * 8);

  f32x16 oacc[2] = {};       // O^T: row d = 32*dm + crow(r,hi), col q = ln
  float mstate = -1e30f, lstate = 0.f;

  const int nt = (q0 >> 6) + 2;
  for (int t = 0; t < nt; ++t) {
    const int kv0 = t * 64;
    __syncthreads();   // previous tile consumed
    #pragma unroll
    for (int i = 0; i < 2; ++i) {
      int cb = (w * 2 + i) * 64;
      int cid = cb + lane;
      int row = cid >> 3, cir = cid & 7;
      int lch = cir ^ (row & 7);   // pre-swizzle source; LDS stays linear
      gload_lds16(K  + ((size_t)bh * S_ + kv0 + row) * D_ + lch * 8, &k_lds[cb * 8]);
      gload_lds16(Vt + ((size_t)bh * D_ + row) * S_ + kv0 + lch * 8, &v_lds[cb * 8]);
    }
    __syncthreads();   // tiles staged (barrier drains vmcnt)

    if (kv0 > qb + 31) continue;   // fully masked for this wave (barriers already done)

    // ---- QK^T ----
    f32x16 s0 = {}, s1 = {};
    #pragma unroll
    for (int kc = 0; kc < 4; ++kc) {
      int ch = (2 * kc + hi) ^ (ln & 7);
      bf16x8 k0 = *(const bf16x8*)&k_lds[ln * 64 + ch * 8];
      bf16x8 k1 = *(const bf16x8*)&k_lds[(32 + ln) * 64 + ch * 8];
      s0 = mfma32(k0, qf[kc], s0);
      s1 = mfma32(k1, qf[kc], s1);
    }

    // causal mask (exactly one partial tile per wave)
    if (t == (qb >> 6)) {
      #pragma unroll
      for (int r = 0; r < 16; ++r) {
        int crow = (r & 3) + 8 * (r >> 2) + 4 * hi;
        if (kv0 + crow > qg)      s0[r] = -1e30f;
        if (kv0 + 32 + crow > qg) s1[r] = -1e30f;
      }
    }

    // ---- online softmax, lane-local ----
    float mt_ = s0[0];
    #pragma unroll
    for (int r = 1; r < 16; ++r) mt_ = fmaxf(mt_, s0[r]);
    #pragma unroll
    for (int r = 0; r < 16; ++r) mt_ = fmaxf(mt_, s1[r]);
    mt_ = fmaxf(mt_, __shfl_xor(mt_, 32, 64));
    bool resc = mt_ > mstate + 8.f;          // defer-max (T13)
    float mnew = resc ? mt_ : mstate;
    float alpha = resc ? exp2f(mstate - mnew) : 1.f;
    mstate = mnew;
    float rs = 0.f;
    #pragma unroll
    for (int r = 0; r < 16; ++r) { float p = exp2f(s0[r] - mnew); s0[r] = p; rs += p; }
    #pragma unroll
    for (int r = 0; r < 16; ++r) { float p = exp2f(s1[r] - mnew); s1[r] = p; rs += p; }
    rs += __shfl_xor(rs, 32, 64);
    lstate = lstate * alpha + rs;
    if (__any(resc)) {
      #pragma unroll
      for (int r = 0; r < 16; ++r) { oacc[0][r] *= alpha; oacc[1][r] *= alpha; }
    }

    // ---- pack P -> PV B-fragments (cvt_pk + permlane32_swap, T12) ----
    // D keeps low lanes, D[hi=1]<-S[hi=0], S[hi=0]<-D[hi=1]. First operand = low-reg pack.
    bf16x8 pf[4];
    #pragma unroll
    for (int mtl = 0; mtl < 2; ++mtl) {
      #pragma unroll
      for (int c = 0; c < 2; ++c) {
        const f32x16& p = mtl ? s1 : s0;
        uint wa = cvtpk(p[8 * c + 0], p[8 * c + 1]);
        uint wb = cvtpk(p[8 * c + 2], p[8 * c + 3]);
        uint wcx = cvtpk(p[8 * c + 4], p[8 * c + 5]);
        uint wd = cvtpk(p[8 * c + 6], p[8 * c + 7]);
        asm("v_permlane32_swap_b32 %0, %1" : "+v"(wa), "+v"(wcx));
        asm("v_permlane32_swap_b32 %0, %1" : "+v"(wb), "+v"(wd));
        union { uint u[4]; bf16x8 v; } cvt;
        cvt.u[0] = wa; cvt.u[1] = wb; cvt.u[2] = wcx; cvt.u[3] = wd;
        pf[mtl * 2 + c] = cvt.v;
      }
    }

    // ---- O^T += Vt * P^T ----
    #pragma unroll
    for (int dm = 0; dm < 2; ++dm) {
      #pragma unroll
      for (int ks = 0; ks < 4; ++ks) {
        int row = dm * 32 + ln;
        int ch = (2 * ks + hi) ^ (ln & 7);
        bf16x8 vf = *(const bf16x8*)&v_lds[row * 64 + ch * 8];
        oacc[dm] = mfma32(vf, pf[ks], oacc[dm]);
      }
    }
  }

  // epilogue: O = O^T / l, packed 8B stores. d = 32*dm + 8*g + 4*hi + i
  float rinv = 1.f / lstate;
  const int b = bh >> 4, h = bh & 15;
  bf16* orow = Oc + ((size_t)(b * S_ + qg)) * E_ + h * D_;
  #pragma unroll
  for (int dm = 0; dm < 2; ++dm) {
    #pragma unroll
    for (int g = 0; g < 4; ++g) {
      bf16x4 st;
      #pragma unroll
      for (int i = 0; i < 4; ++i) st[i] = (bf16)(oacc[dm][4 * g + i] * rinv);
      *(bf16x4*)(orow + dm * 32 + g * 8 + hi * 4) = st;
    }
  }
}

// ---------- launcher ----------
extern "C" void kernel_launch(void* const* d_in, const int* in_sizes, int n_in,
                              void* d_out, int out_size, void* d_ws, size_t ws_size,
                              hipStream_t stream) {
  const float* x  = (const float*)d_in[0];
  const float* Wq = (const float*)d_in[1];
  const float* bq = (const float*)d_in[2];
  const float* Wk = (const float*)d_in[3];
  const float* bk = (const float*)d_in[4];
  const float* Wv = (const float*)d_in[5];
  const float* bv = (const float*)d_in[6];
  const float* Wo = (const float*)d_in[7];
  const float* bo = (const float*)d_in[8];
  float* out = (float*)d_out;

  uint8_t* ws = (uint8_t*)d_ws;
  bf16* Xbf   = (bf16*)(ws + 0);           // [M][K]; later reused as concat
  bf16* Wpack = (bf16*)(ws + 16777216);    // [3072][1024]
  bf16* Wot   = (bf16*)(ws + 23068672);    // [1024][1024]
  bf16* Qb    = (bf16*)(ws + 25165824);    // [B,H,S,D] (pre-scaled)
  bf16* Kb    = (bf16*)(ws + 41943040);
  bf16* Vb    = (bf16*)(ws + 58720256);
  bf16* Vtb   = (bf16*)(ws + 75497472);    // [B,H,D,S]
  bf16* Cc    = Xbf;

  cast_f32_bf16<<<2048, 256, 0, stream>>>(x,  Xbf, (M_ * K_) / 4);
  cast_f32_bf16<<<1024, 256, 0, stream>>>(Wo, Wot, (E_ * E_) / 4);
  pack_w_t<<<dim3(16, 48), 256, 0, stream>>>(Wq, Wk, Wv, Wpack);

  gemm_kernel<0><<<dim3(64 * 24), 256, 0, stream>>>(Xbf, Wpack, 3072, bq, bk, bv,
                                                    Qb, Kb, Vb, nullptr);
  transpose_v<<<dim3(S_ / 64, B_ * H_), 256, 0, stream>>>(Vb, Vtb);

  attn_kernel<<<dim3(16, B_ * H_), 256, 0, stream>>>(Qb, Kb, Vtb, Cc);

  gemm_kernel<1><<<dim3(64 * 8), 256, 0, stream>>>(Cc, Wot, 1024, bo, nullptr, nullptr,
                                                   nullptr, nullptr, nullptr, out);
}

// Round 4
// 198.527 us; speedup vs baseline: 1.7199x; 1.2194x over previous
//
#include <hip/hip_runtime.h>
#include <stdint.h>
#include <stddef.h>

// ---------- types ----------
typedef __bf16 bf16;
typedef __bf16 bf16x8 __attribute__((ext_vector_type(8)));
typedef __bf16 bf16x4 __attribute__((ext_vector_type(4)));
typedef float  f32x4  __attribute__((ext_vector_type(4)));
typedef float  f32x16 __attribute__((ext_vector_type(16)));
typedef unsigned short ush;
typedef ush ush8 __attribute__((ext_vector_type(8)));
typedef unsigned int uint;

// ---------- problem sizes ----------
#define B_  4
#define S_  2048
#define E_  1024
#define H_  16
#define D_  64
#define M_  (B_*S_)      // 8192 rows
#define K_  E_           // 1024 reduction
// 0.125 (1/sqrt(D)) * log2(e): QKV epilogue folds this into Q -> softmax in exp2 domain
#define QSCALE 0.18033688011112042f

// ---------- helpers ----------
__device__ __forceinline__ void gload_lds16(const void* g, void* l) {
  __builtin_amdgcn_global_load_lds((const __attribute__((address_space(1))) void*)g,
                                   (__attribute__((address_space(3))) void*)l, 16, 0, 0);
}
__device__ __forceinline__ f32x4 mfma16(bf16x8 a, bf16x8 b, f32x4 c) {
  return __builtin_amdgcn_mfma_f32_16x16x32_bf16(a, b, c, 0, 0, 0);
}
__device__ __forceinline__ f32x16 mfma32(bf16x8 a, bf16x8 b, f32x16 c) {
  return __builtin_amdgcn_mfma_f32_32x32x16_bf16(a, b, c, 0, 0, 0);
}
__device__ __forceinline__ int swz4(int row, int ch) { return ch ^ ((row >> 1) & 3); }
__device__ __forceinline__ uint cvtpk(float lo, float hi) {
  uint r;
  asm("v_cvt_pk_bf16_f32 %0, %1, %2" : "=v"(r) : "v"(lo), "v"(hi));
  return r;
}

// ---------- prep kernels ----------
__global__ void cast_f32_bf16(const float* __restrict__ src, bf16* __restrict__ dst, int n4) {
  int idx = blockIdx.x * blockDim.x + threadIdx.x;
  int stride = gridDim.x * blockDim.x;
  for (int i = idx; i < n4; i += stride) {
    float4 v = ((const float4*)src)[i];
    union { bf16 b[4]; ushort4 u; } cv;
    cv.b[0] = (bf16)v.x; cv.b[1] = (bf16)v.y; cv.b[2] = (bf16)v.z; cv.b[3] = (bf16)v.w;
    ((ushort4*)dst)[i] = cv.u;
  }
}

// pack Wq|Wk|Wv [H,E,D] -> Wp[n][e], n = which*1024 + h*64 + d. LDS-tiled transpose.
__global__ void pack_w_t(const float* __restrict__ Wq, const float* __restrict__ Wk,
                         const float* __restrict__ Wv, bf16* __restrict__ Wp) {
  __shared__ float t[64][65];
  const int tid = threadIdx.x;
  const int wh = blockIdx.y;          // 0..47
  const int which = wh >> 4, h = wh & 15;
  const int e0 = blockIdx.x << 6;
  const float* src = (which == 0) ? Wq : (which == 1 ? Wk : Wv);
  src += (size_t)h * (E_ * D_);       // [E][D] for this head
  #pragma unroll
  for (int i = 0; i < 4; ++i) {
    int fi = tid + 256 * i;
    int e = fi >> 4, c = fi & 15;
    float4 v = *(const float4*)(src + (size_t)(e0 + e) * D_ + c * 4);
    t[c * 4 + 0][e] = v.x; t[c * 4 + 1][e] = v.y;
    t[c * 4 + 2][e] = v.z; t[c * 4 + 3][e] = v.w;
  }
  __syncthreads();
  #pragma unroll
  for (int i = 0; i < 2; ++i) {
    int cid = tid + 256 * i;
    int d = cid >> 3, cc = cid & 7;
    ush8 o;
    #pragma unroll
    for (int j = 0; j < 8; ++j) {
      union { bf16 b; ush u; } cv; cv.b = (bf16)t[d][cc * 8 + j]; o[j] = cv.u;
    }
    *(ush8*)(Wp + ((size_t)which * 1024 + h * 64 + d) * K_ + e0 + cc * 8) = o;
  }
}

// ---------- GEMM: C[M][N] = A[M][K] * Bm[N][K]^T ----------
template <int MODE>
__launch_bounds__(256, 2)
__global__ void gemm_kernel(const bf16* __restrict__ A, const bf16* __restrict__ Bm,
                            int Ntot,
                            const float* __restrict__ bias0, const float* __restrict__ bias1,
                            const float* __restrict__ bias2,
                            bf16* __restrict__ Qo, bf16* __restrict__ Ko, bf16* __restrict__ Vo,
                            float* __restrict__ Fo) {
  __shared__ __align__(16) bf16 lds_a[2][128 * 32];
  __shared__ __align__(16) bf16 lds_b[2][128 * 32];
  const int tid = threadIdx.x;
  const int lane = tid & 63;
  const int w = tid >> 6;
  const int wr = w >> 1, wc = w & 1;
  const int nblk = Ntot >> 7;
  const int mt = blockIdx.x / nblk, nt = blockIdx.x % nblk;
  const int m0 = mt << 7, n0 = nt << 7;

  f32x4 acc[4][4] = {};

  auto stage = [&](int buf, int kt) {
    #pragma unroll
    for (int i = 0; i < 2; ++i) {
      int cb = (w * 2 + i) * 64;
      int cid = cb + lane;
      int row = cid >> 2, cir = cid & 3;
      int lch = swz4(row, cir);
      const bf16* ga = A  + (size_t)(m0 + row) * K_ + kt * 32 + lch * 8;
      const bf16* gb = Bm + (size_t)(n0 + row) * K_ + kt * 32 + lch * 8;
      gload_lds16(ga, &lds_a[buf][cb * 8]);
      gload_lds16(gb, &lds_b[buf][cb * 8]);
    }
  };

  const int NT = K_ / 32;
  stage(0, 0);
  for (int kt = 0; kt < NT; ++kt) {
    if (kt + 1 < NT) stage((kt + 1) & 1, kt + 1);
    __syncthreads();
    const bf16x8* pa = (const bf16x8*)&lds_a[kt & 1][0];
    const bf16x8* pb = (const bf16x8*)&lds_b[kt & 1][0];
    bf16x8 af[4], bfr[4];
    #pragma unroll
    for (int mb = 0; mb < 4; ++mb) {
      int row = wr * 64 + mb * 16 + (lane & 15);
      af[mb] = pa[row * 4 + swz4(row, lane >> 4)];
    }
    #pragma unroll
    for (int nb = 0; nb < 4; ++nb) {
      int row = wc * 64 + nb * 16 + (lane & 15);
      bfr[nb] = pb[row * 4 + swz4(row, lane >> 4)];
    }
    #pragma unroll
    for (int mb = 0; mb < 4; ++mb)
      #pragma unroll
      for (int nb = 0; nb < 4; ++nb)
        acc[mb][nb] = mfma16(af[mb], bfr[nb], acc[mb][nb]);
    __syncthreads();
  }

  #pragma unroll
  for (int mb = 0; mb < 4; ++mb) {
    #pragma unroll
    for (int nb = 0; nb < 4; ++nb) {
      #pragma unroll
      for (int r = 0; r < 4; ++r) {
        int mi = m0 + wr * 64 + mb * 16 + (lane >> 4) * 4 + r;
        int ni = n0 + wc * 64 + nb * 16 + (lane & 15);
        float v = acc[mb][nb][r];
        if (MODE == 0) {
          int which = ni >> 10;
          int col = ni & 1023;
          const float* bp = (which == 0) ? bias0 : (which == 1 ? bias1 : bias2);
          v += bp[col];
          if (which == 0) v *= QSCALE;   // fold 1/sqrt(D)*log2e into Q
          int h = col >> 6, d = col & 63;
          int b = mi >> 11, s = mi & 2047;
          bf16* dst = (which == 0) ? Qo : (which == 1 ? Ko : Vo);
          dst[(((size_t)(b * H_ + h)) * S_ + s) * D_ + d] = (bf16)v;
        } else {
          Fo[(size_t)mi * E_ + ni] = v + bias0[ni];
        }
      }
    }
  }
}

// ---------- V transpose: V[B,H,S,D] -> Vt[B,H,D,S] ----------
__global__ void transpose_v(const bf16* __restrict__ V, bf16* __restrict__ Vt) {
  __shared__ ush t[64 * 65];
  const int bh = blockIdx.y;
  const int s0 = blockIdx.x * 64;
  const int tid = threadIdx.x;
  #pragma unroll
  for (int i = 0; i < 2; ++i) {
    int cid = tid + 256 * i;
    int r = cid >> 3, c = cid & 7;
    ush8 val = *(const ush8*)(V + ((size_t)bh * S_ + s0 + r) * D_ + c * 8);
    #pragma unroll
    for (int j = 0; j < 8; ++j) t[(c * 8 + j) * 65 + r] = val[j];
  }
  __syncthreads();
  #pragma unroll
  for (int i = 0; i < 2; ++i) {
    int cid = tid + 256 * i;
    int d = cid >> 3, sc = cid & 7;
    ush8 o;
    #pragma unroll
    for (int j = 0; j < 8; ++j) o[j] = t[d * 65 + sc * 8 + j];
    *(ush8*)(Vt + ((size_t)bh * D_ + d) * S_ + s0 + sc * 8) = o;
  }
}

// ---------- flash attention (causal), swapped-QK^T 32x32, paired q-tiles ----------
struct QTile {
  bf16x8 qf[4];
  f32x16 oacc[2];
  float m, l;
};

__device__ __forceinline__ void init_q(QTile& S, const bf16* qrow, int hi) {
  #pragma unroll
  for (int kc = 0; kc < 4; ++kc)
    S.qf[kc] = *(const bf16x8*)(qrow + (2 * kc + hi) * 8);
  #pragma unroll
  for (int r = 0; r < 16; ++r) { S.oacc[0][r] = 0.f; S.oacc[1][r] = 0.f; }
  S.m = -1e30f; S.l = 0.f;
}

__device__ __forceinline__ void tile_step(QTile& S, const bf16* klds, const bf16* vlds,
                                          int kv0, int qb_, int qg_, int hi, int ln) {
  if (kv0 > qb_ + 31) return;   // fully masked for this wave
  // ---- QK^T (S^T = mfma(K, Q)): lane owns q=ln; kv regs crow(r,hi) ----
  f32x16 s0 = {}, s1 = {};
  #pragma unroll
  for (int kc = 0; kc < 4; ++kc) {
    int ch = (2 * kc + hi) ^ (ln & 7);
    bf16x8 k0 = *(const bf16x8*)&klds[ln * 64 + ch * 8];
    bf16x8 k1 = *(const bf16x8*)&klds[(32 + ln) * 64 + ch * 8];
    s0 = mfma32(k0, S.qf[kc], s0);
    s1 = mfma32(k1, S.qf[kc], s1);
  }
  // causal mask (only the wave's last tile is partial)
  if (kv0 + 63 > qb_) {
    #pragma unroll
    for (int r = 0; r < 16; ++r) {
      int crow = (r & 3) + 8 * (r >> 2) + 4 * hi;
      if (kv0 + crow > qg_)      s0[r] = -1e30f;
      if (kv0 + 32 + crow > qg_) s1[r] = -1e30f;
    }
  }
  // ---- online softmax, lane-local (exp2 domain) ----
  float mt_ = s0[0];
  #pragma unroll
  for (int r = 1; r < 16; ++r) mt_ = fmaxf(mt_, s0[r]);
  #pragma unroll
  for (int r = 0; r < 16; ++r) mt_ = fmaxf(mt_, s1[r]);
  mt_ = fmaxf(mt_, __shfl_xor(mt_, 32, 64));
  bool resc = mt_ > S.m + 8.f;          // defer-max (T13)
  float mnew = resc ? mt_ : S.m;
  float alpha = resc ? exp2f(S.m - mnew) : 1.f;
  S.m = mnew;
  float rs = 0.f;
  #pragma unroll
  for (int r = 0; r < 16; ++r) { float p = exp2f(s0[r] - mnew); s0[r] = p; rs += p; }
  #pragma unroll
  for (int r = 0; r < 16; ++r) { float p = exp2f(s1[r] - mnew); s1[r] = p; rs += p; }
  rs += __shfl_xor(rs, 32, 64);
  S.l = S.l * alpha + rs;
  if (__any(resc)) {
    #pragma unroll
    for (int r = 0; r < 16; ++r) { S.oacc[0][r] *= alpha; S.oacc[1][r] *= alpha; }
  }
  // ---- pack P -> PV B-fragments (cvt_pk + permlane32_swap, T12) ----
  bf16x8 pf[4];
  #pragma unroll
  for (int mtl = 0; mtl < 2; ++mtl) {
    #pragma unroll
    for (int c = 0; c < 2; ++c) {
      const f32x16& p = mtl ? s1 : s0;
      uint wa = cvtpk(p[8 * c + 0], p[8 * c + 1]);
      uint wb = cvtpk(p[8 * c + 2], p[8 * c + 3]);
      uint wcx = cvtpk(p[8 * c + 4], p[8 * c + 5]);
      uint wd = cvtpk(p[8 * c + 6], p[8 * c + 7]);
      asm("v_permlane32_swap_b32 %0, %1" : "+v"(wa), "+v"(wcx));
      asm("v_permlane32_swap_b32 %0, %1" : "+v"(wb), "+v"(wd));
      union { uint u[4]; bf16x8 v; } cvt;
      cvt.u[0] = wa; cvt.u[1] = wb; cvt.u[2] = wcx; cvt.u[3] = wd;
      pf[mtl * 2 + c] = cvt.v;
    }
  }
  // ---- O^T += Vt * P^T ----
  #pragma unroll
  for (int dm = 0; dm < 2; ++dm) {
    #pragma unroll
    for (int ks = 0; ks < 4; ++ks) {
      int row = dm * 32 + ln;
      int ch = (2 * ks + hi) ^ (ln & 7);
      bf16x8 vf = *(const bf16x8*)&vlds[row * 64 + ch * 8];
      oaccum:
      S.oacc[dm] = mfma32(vf, pf[ks], S.oacc[dm]);
    }
  }
}

__device__ __forceinline__ void store_o(const QTile& S, bf16* orow, int hi) {
  float rinv = 1.f / S.l;
  #pragma unroll
  for (int dm = 0; dm < 2; ++dm) {
    #pragma unroll
    for (int g = 0; g < 4; ++g) {
      bf16x4 st;
      #pragma unroll
      for (int i = 0; i < 4; ++i) st[i] = (bf16)(S.oacc[dm][4 * g + i] * rinv);
      *(bf16x4*)(orow + dm * 32 + g * 8 + hi * 4) = st;
    }
  }
}

// 1D grid of 512 blocks; bid&7 = bh&7 so the 8 blocks sharing a bh land on one XCD.
// Block handles q-tiles {x, 15-x}: uniform total work, merged kv loop shares K/V tiles.
__launch_bounds__(256, 2)
__global__ void attn_kernel(const bf16* __restrict__ Q, const bf16* __restrict__ K,
                            const bf16* __restrict__ Vt, bf16* __restrict__ Oc) {
  __shared__ __align__(16) bf16 k_lds[2][64 * 64];
  __shared__ __align__(16) bf16 v_lds[2][64 * 64];
  const int tid = threadIdx.x, lane = tid & 63, w = tid >> 6;
  const int hi = lane >> 5, ln = lane & 31;
  const int bid = blockIdx.x;
  const int bh = (bid & 7) | ((bid >> 6) << 3);
  const int x  = (bid >> 3) & 7;
  const int jta = x, jtb = 15 - x;
  const int qba = (jta << 7) + w * 32, qbb = (jtb << 7) + w * 32;
  const int qga = qba + ln, qgb = qbb + ln;
  const int nta = 2 * jta + 2, ntb = 2 * jtb + 2;

  QTile A, B;
  init_q(A, Q + ((size_t)bh * S_ + qga) * D_, hi);
  init_q(B, Q + ((size_t)bh * S_ + qgb) * D_, hi);

  auto stage = [&](int buf, int t) {
    const int kv0 = t << 6;
    #pragma unroll
    for (int i = 0; i < 2; ++i) {
      int cb = (w * 2 + i) * 64;
      int cid = cb + lane;
      int row = cid >> 3, cir = cid & 7;
      int lch = cir ^ (row & 7);   // pre-swizzle source; LDS stays linear
      gload_lds16(K  + ((size_t)bh * S_ + kv0 + row) * D_ + lch * 8, &k_lds[buf][cb * 8]);
      gload_lds16(Vt + ((size_t)bh * D_ + row) * S_ + kv0 + lch * 8, &v_lds[buf][cb * 8]);
    }
  };

  stage(0, 0);
  __syncthreads();                 // drain prologue stage
  for (int t = 0; t < ntb; ++t) {
    const int cur = t & 1;
    if (t + 1 < ntb) stage(cur ^ 1, t + 1);   // issue next tile (in flight under compute)
    const int kv0 = t << 6;
    if (t < nta) tile_step(A, k_lds[cur], v_lds[cur], kv0, qba, qga, hi, ln);
    tile_step(B, k_lds[cur], v_lds[cur], kv0, qbb, qgb, hi, ln);
    __syncthreads();               // vmcnt(0)+lgkm drain AFTER compute; buffers swap-safe
  }

  const int b = bh >> 4, h = bh & 15;
  store_o(A, Oc + ((size_t)(b * S_ + qga)) * E_ + h * D_, hi);
  store_o(B, Oc + ((size_t)(b * S_ + qgb)) * E_ + h * D_, hi);
}

// ---------- launcher ----------
extern "C" void kernel_launch(void* const* d_in, const int* in_sizes, int n_in,
                              void* d_out, int out_size, void* d_ws, size_t ws_size,
                              hipStream_t stream) {
  const float* x  = (const float*)d_in[0];
  const float* Wq = (const float*)d_in[1];
  const float* bq = (const float*)d_in[2];
  const float* Wk = (const float*)d_in[3];
  const float* bk = (const float*)d_in[4];
  const float* Wv = (const float*)d_in[5];
  const float* bv = (const float*)d_in[6];
  const float* Wo = (const float*)d_in[7];
  const float* bo = (const float*)d_in[8];
  float* out = (float*)d_out;

  uint8_t* ws = (uint8_t*)d_ws;
  bf16* Xbf   = (bf16*)(ws + 0);           // [M][K]; later reused as concat
  bf16* Wpack = (bf16*)(ws + 16777216);    // [3072][1024]
  bf16* Wot   = (bf16*)(ws + 23068672);    // [1024][1024]
  bf16* Qb    = (bf16*)(ws + 25165824);    // [B,H,S,D] (pre-scaled)
  bf16* Kb    = (bf16*)(ws + 41943040);
  bf16* Vb    = (bf16*)(ws + 58720256);
  bf16* Vtb   = (bf16*)(ws + 75497472);    // [B,H,D,S]
  bf16* Cc    = Xbf;

  cast_f32_bf16<<<2048, 256, 0, stream>>>(x,  Xbf, (M_ * K_) / 4);
  cast_f32_bf16<<<1024, 256, 0, stream>>>(Wo, Wot, (E_ * E_) / 4);
  pack_w_t<<<dim3(16, 48), 256, 0, stream>>>(Wq, Wk, Wv, Wpack);

  gemm_kernel<0><<<dim3(64 * 24), 256, 0, stream>>>(Xbf, Wpack, 3072, bq, bk, bv,
                                                    Qb, Kb, Vb, nullptr);
  transpose_v<<<dim3(S_ / 64, B_ * H_), 256, 0, stream>>>(Vb, Vtb);

  attn_kernel<<<512, 256, 0, stream>>>(Qb, Kb, Vtb, Cc);

  gemm_kernel<1><<<dim3(64 * 8), 256, 0, stream>>>(Cc, Wot, 1024, bo, nullptr, nullptr,
                                                   nullptr, nullptr, nullptr, out);
}